// Round 4
// baseline (456.055 us; speedup 1.0000x reference)
//
#include <hip/hip_runtime.h>

#define HID 128
#define INP 64
#define LN_EPS 1e-5f
#define RT 64   // rows per block in GEMM kernels

typedef __attribute__((ext_vector_type(8))) short bf16x8;
typedef __attribute__((ext_vector_type(4))) float f32x4;

__device__ __forceinline__ unsigned f2bf(float f) {
    unsigned u = __float_as_uint(f);
    return (u + 0x7FFFu + ((u >> 16) & 1u)) >> 16;   // RNE
}
__device__ __forceinline__ float bflo(unsigned v) { return __uint_as_float(v << 16); }
__device__ __forceinline__ float bfhi(unsigned v) { return __uint_as_float(v & 0xFFFF0000u); }

// ---------------- CSR build ----------------
__global__ void k_count(const int* __restrict__ dst, int nE, int* __restrict__ cnt) {
    int e = blockIdx.x * blockDim.x + threadIdx.x;
    if (e < nE) atomicAdd(&cnt[dst[e]], 1);
}

__global__ void k_scan1(const int* __restrict__ cnt, int n, int* __restrict__ rowp, int* __restrict__ bsum) {
    __shared__ int s[256];
    int i = blockIdx.x * 256 + threadIdx.x;
    int v = (i < n) ? cnt[i] : 0;
    s[threadIdx.x] = v;
    __syncthreads();
    for (int off = 1; off < 256; off <<= 1) {
        int t = (threadIdx.x >= off) ? s[threadIdx.x - off] : 0;
        __syncthreads();
        s[threadIdx.x] += t;
        __syncthreads();
    }
    if (i < n) rowp[i] = s[threadIdx.x] - v;  // exclusive
    if (threadIdx.x == 255) bsum[blockIdx.x] = s[255];
}

__global__ void k_scan2(int* __restrict__ bsum, int nb) {
    __shared__ int s[256];
    int v = (threadIdx.x < nb) ? bsum[threadIdx.x] : 0;
    s[threadIdx.x] = v;
    __syncthreads();
    for (int off = 1; off < 256; off <<= 1) {
        int t = (threadIdx.x >= off) ? s[threadIdx.x - off] : 0;
        __syncthreads();
        s[threadIdx.x] += t;
        __syncthreads();
    }
    if (threadIdx.x < nb) bsum[threadIdx.x] = s[threadIdx.x] - v;
}

__global__ void k_scan3(int* __restrict__ rowp, const int* __restrict__ bsum, const int* __restrict__ cnt,
                        int n, int nE, int* __restrict__ cursor, float* __restrict__ invd) {
    int i = blockIdx.x * 256 + threadIdx.x;
    if (i < n) {
        int rp = rowp[i] + bsum[blockIdx.x];
        rowp[i] = rp;
        cursor[i] = rp;
        int c = cnt[i];
        invd[i] = 1.0f / (float)(c > 1 ? c : 1);
    } else if (i == n) {
        rowp[n] = nE;
    }
}

__global__ void k_fill(const int* __restrict__ src, const int* __restrict__ dst, int nE,
                       int* __restrict__ cursor, int* __restrict__ csrc) {
    int e = blockIdx.x * blockDim.x + threadIdx.x;
    if (e < nE) {
        int p = atomicAdd(&cursor[dst[e]], 1);
        csrc[p] = src[e];
    }
}

// ---------------- weight prep: transpose + bf16 convert ----------------
__global__ void w_prep(const float* __restrict__ W_in, const float* __restrict__ W_l,
                       unsigned short* __restrict__ Wt_in, unsigned short* __restrict__ Wt_l) {
    int i = blockIdx.x * 256 + threadIdx.x;
    if (i < 128 * 64) {
        int col = i >> 6, k = i & 63;
        Wt_in[i] = (unsigned short)f2bf(W_in[(size_t)k * HID + col]);
    }
    int j = i - 128 * 64;
    if (j >= 0 && j < 3 * 128 * 128) {
        int l = j >> 14, r = j & 16383;
        int col = r >> 7, k = r & 127;
        Wt_l[j] = (unsigned short)f2bf(W_l[(size_t)l * 16384 + (size_t)k * HID + col]);
    }
}

// ---------------- in-projection (MFMA): hb = bf16(x @ W_in + b_in) ----------------
__global__ __launch_bounds__(256) void k_inproj(const float* __restrict__ x,
                                                const unsigned short* __restrict__ Wt,  // [128][64] bf16
                                                const float* __restrict__ b,
                                                unsigned* __restrict__ hout, int n) {
    __shared__ unsigned short xs[RT * INP];  // 8 KB, swizzled
    const int tid = threadIdx.x;
    const int row0 = blockIdx.x * RT;

#pragma unroll
    for (int j = 0; j < 2; ++j) {
        int fid = tid + j * 256;
        int r = fid >> 3, c = fid & 7;
        int grow = row0 + r;
        unsigned o[4] = {0, 0, 0, 0};
        if (grow < n) {
            float4 v0 = *reinterpret_cast<const float4*>(x + (size_t)grow * INP + c * 8);
            float4 v1 = *reinterpret_cast<const float4*>(x + (size_t)grow * INP + c * 8 + 4);
            o[0] = f2bf(v0.x) | (f2bf(v0.y) << 16);
            o[1] = f2bf(v0.z) | (f2bf(v0.w) << 16);
            o[2] = f2bf(v1.x) | (f2bf(v1.y) << 16);
            o[3] = f2bf(v1.z) | (f2bf(v1.w) << 16);
        }
        int sw = c ^ (r & 7);
        *reinterpret_cast<uint4*>(xs + r * INP + sw * 8) = make_uint4(o[0], o[1], o[2], o[3]);
    }
    __syncthreads();

    const int l = tid & 63;
    const int w = tid >> 6;
    const int l15 = l & 15, lg = l >> 4;
    const int xrow = w * 16 + l15;

    f32x4 acc[8];
#pragma unroll
    for (int t = 0; t < 8; ++t) acc[t] = (f32x4){0.f, 0.f, 0.f, 0.f};

#pragma unroll
    for (int kc = 0; kc < 2; ++kc) {
        int bc = (kc * 4 + lg) ^ (xrow & 7);
        bf16x8 bfrag = *reinterpret_cast<const bf16x8*>(xs + xrow * INP + bc * 8);
        const unsigned short* wp = Wt + (size_t)l15 * INP + kc * 32 + lg * 8;
        bf16x8 af[8];
#pragma unroll
        for (int t = 0; t < 8; ++t) af[t] = *reinterpret_cast<const bf16x8*>(wp + (size_t)t * 16 * INP);
#pragma unroll
        for (int t = 0; t < 8; ++t)
            acc[t] = __builtin_amdgcn_mfma_f32_16x16x32_bf16(af[t], bfrag, acc[t], 0, 0, 0);
    }

    int grow = row0 + xrow;
    if (grow < n) {
#pragma unroll
        for (int t = 0; t < 8; ++t) {
            int c0 = t * 16 + lg * 4;
            f32x4 bb = *reinterpret_cast<const f32x4*>(b + c0);
            f32x4 o = acc[t] + bb;
            uint2 p;
            p.x = f2bf(o.x) | (f2bf(o.y) << 16);
            p.y = f2bf(o.z) | (f2bf(o.w) << 16);
            *reinterpret_cast<uint2*>(hout + (size_t)grow * 64 + t * 8 + lg * 2) = p;
        }
    }
}

// ---------------- fused layer (gather + MFMA): hout = relu(LN((hin+agg)@W + b)*g + lnb) + hin ----------------
__global__ __launch_bounds__(256) void k_layer(const unsigned* __restrict__ hin,  // [n*64] bf16 pairs
                                               unsigned* __restrict__ hout,
                                               const int* __restrict__ rowp, const int* __restrict__ csrc,
                                               const float* __restrict__ invd,
                                               const unsigned short* __restrict__ Wt,  // [128][128] bf16
                                               const float* __restrict__ bias, const float* __restrict__ g,
                                               const float* __restrict__ lnb, int n) {
    __shared__ unsigned short xs[RT * HID];  // 16 KB, swizzled
    const int tid = threadIdx.x;
    const int row0 = blockIdx.x * RT;
    const int lane = tid & 63;
    const int w = tid >> 6;

    // ---- phase 1: gather-aggregate; X = hin + agg -> bf16 -> swizzled LDS ----
    // wave w handles rows w*16 .. w*16+15; lane covers 2 cols (one bf16 pair)
#pragma unroll 1
    for (int ni = 0; ni < 16; ++ni) {
        int r = w * 16 + ni;
        int node = row0 + r;
        unsigned o = 0;
        if (node < n) {
            int e0 = rowp[node], e1 = rowp[node + 1];
            float ax = 0.f, ay = 0.f;
            int e = e0;
            for (; e + 4 <= e1; e += 4) {
                int s0 = csrc[e], s1 = csrc[e + 1], s2 = csrc[e + 2], s3 = csrc[e + 3];
                unsigned v0 = hin[(size_t)s0 * 64 + lane];
                unsigned v1 = hin[(size_t)s1 * 64 + lane];
                unsigned v2 = hin[(size_t)s2 * 64 + lane];
                unsigned v3 = hin[(size_t)s3 * 64 + lane];
                ax += (bflo(v0) + bflo(v1)) + (bflo(v2) + bflo(v3));
                ay += (bfhi(v0) + bfhi(v1)) + (bfhi(v2) + bfhi(v3));
            }
            for (; e < e1; ++e) {
                unsigned v = hin[(size_t)csrc[e] * 64 + lane];
                ax += bflo(v);
                ay += bfhi(v);
            }
            float inv = invd[node];
            unsigned self = hin[(size_t)node * 64 + lane];
            float xlo = bflo(self) + ax * inv;
            float xhi = bfhi(self) + ay * inv;
            o = f2bf(xlo) | (f2bf(xhi) << 16);
        }
        int c = lane >> 2;
        int sw = c ^ (r & 7);
        *reinterpret_cast<unsigned*>(xs + r * HID + sw * 8 + (lane & 3) * 2) = o;
    }
    __syncthreads();

    // ---- phase 2: MFMA + LN + relu + residual ----
    const int l15 = lane & 15, lg = lane >> 4;
    const int xrow = w * 16 + l15;

    f32x4 acc[8];
#pragma unroll
    for (int t = 0; t < 8; ++t) acc[t] = (f32x4){0.f, 0.f, 0.f, 0.f};

#pragma unroll
    for (int kc = 0; kc < 4; ++kc) {
        int bc = (kc * 4 + lg) ^ (xrow & 7);
        bf16x8 bfrag = *reinterpret_cast<const bf16x8*>(xs + xrow * HID + bc * 8);
        const unsigned short* wp = Wt + (size_t)l15 * HID + kc * 32 + lg * 8;
        bf16x8 af[8];
#pragma unroll
        for (int t = 0; t < 8; ++t) af[t] = *reinterpret_cast<const bf16x8*>(wp + (size_t)t * 16 * HID);
#pragma unroll
        for (int t = 0; t < 8; ++t)
            acc[t] = __builtin_amdgcn_mfma_f32_16x16x32_bf16(af[t], bfrag, acc[t], 0, 0, 0);
    }

    float s = 0.f, q = 0.f;
#pragma unroll
    for (int t = 0; t < 8; ++t) {
        int c0 = t * 16 + lg * 4;
        f32x4 bb = *reinterpret_cast<const f32x4*>(bias + c0);
        acc[t] = acc[t] + bb;
        s += acc[t].x + acc[t].y + acc[t].z + acc[t].w;
        q += acc[t].x * acc[t].x + acc[t].y * acc[t].y + acc[t].z * acc[t].z + acc[t].w * acc[t].w;
    }
    s += __shfl_xor(s, 16, 64);
    s += __shfl_xor(s, 32, 64);
    q += __shfl_xor(q, 16, 64);
    q += __shfl_xor(q, 32, 64);
    float mu = s * (1.0f / HID);
    float var = q * (1.0f / HID) - mu * mu;
    float rs = rsqrtf(var + LN_EPS);

    int grow = row0 + xrow;
    if (grow < n) {
#pragma unroll
        for (int t = 0; t < 8; ++t) {
            int c0 = t * 16 + lg * 4;
            uint2 rv = *reinterpret_cast<const uint2*>(hin + (size_t)grow * 64 + t * 8 + lg * 2);
            f32x4 gv = *reinterpret_cast<const f32x4*>(g + c0);
            f32x4 lb = *reinterpret_cast<const f32x4*>(lnb + c0);
            float o0 = fmaxf((acc[t].x - mu) * rs * gv.x + lb.x, 0.f) + bflo(rv.x);
            float o1 = fmaxf((acc[t].y - mu) * rs * gv.y + lb.y, 0.f) + bfhi(rv.x);
            float o2 = fmaxf((acc[t].z - mu) * rs * gv.z + lb.z, 0.f) + bflo(rv.y);
            float o3 = fmaxf((acc[t].w - mu) * rs * gv.w + lb.w, 0.f) + bfhi(rv.y);
            uint2 p;
            p.x = f2bf(o0) | (f2bf(o1) << 16);
            p.y = f2bf(o2) | (f2bf(o3) << 16);
            *reinterpret_cast<uint2*>(hout + (size_t)grow * 64 + t * 8 + lg * 2) = p;
        }
    }
}

// ---------------- final: accum[c] = sum over rows < n_act of h[r][c] ----------------
__global__ void k_rowsum(const unsigned* __restrict__ hb, const int* __restrict__ n_act_p,
                         float* __restrict__ accum, int n) {
    int na = *n_act_p;
    int row0 = blockIdx.x * 256;
    int c = threadIdx.x;  // 0..63, col pair
    int rend = row0 + 256;
    if (rend > na) rend = na;
    float sx = 0.f, sy = 0.f;
    for (int r = row0; r < rend; ++r) {
        unsigned v = hb[(size_t)r * 64 + c];
        sx += bflo(v);
        sy += bfhi(v);
    }
    if (row0 < na) {
        atomicAdd(&accum[2 * c], sx);
        atomicAdd(&accum[2 * c + 1], sy);
    }
}

__global__ void k_out(const float* __restrict__ accum, const int* __restrict__ n_act_p,
                      const float* __restrict__ W_out, const float* __restrict__ b_out,
                      float* __restrict__ out) {
    __shared__ float m[HID];
    int c = threadIdx.x;
    float na = (float)(*n_act_p);
    m[c] = accum[c] / na;
    __syncthreads();
    float s = b_out[c];
    for (int k = 0; k < HID; ++k) s += m[k] * W_out[k * HID + c];
    out[c] = s;
}

extern "C" void kernel_launch(void* const* d_in, const int* in_sizes, int n_in,
                              void* d_out, int out_size, void* d_ws, size_t ws_size,
                              hipStream_t stream) {
    const int n  = in_sizes[0] / INP;   // 50000
    const int nE = in_sizes[1] / 2;     // 800000
    const float* x    = (const float*)d_in[0];
    const int*   ei   = (const int*)d_in[1];
    const int*   src  = ei;
    const int*   dst  = ei + nE;
    const int*   nact = (const int*)d_in[2];
    const float* W_in = (const float*)d_in[3];
    const float* b_in = (const float*)d_in[4];
    const float* W_l  = (const float*)d_in[5];
    const float* b_l  = (const float*)d_in[6];
    const float* lng  = (const float*)d_in[7];
    const float* lnb  = (const float*)d_in[8];
    const float* W_o  = (const float*)d_in[9];
    const float* b_o  = (const float*)d_in[10];

    char* ws = (char*)d_ws;
    size_t off = 0;
    auto alloc = [&](size_t bytes) {
        void* p = ws + off;
        off = (off + bytes + 255) & ~((size_t)255);
        return p;
    };
    unsigned* hbA = (unsigned*)alloc((size_t)n * 64 * 4);
    unsigned* hbB = (unsigned*)alloc((size_t)n * 64 * 4);
    int*   cnt  = (int*)alloc((size_t)n * 4);
    int*   rowp = (int*)alloc((size_t)(n + 1) * 4);
    int*   curs = (int*)alloc((size_t)n * 4);
    float* invd = (float*)alloc((size_t)n * 4);
    int*   csrc = (int*)alloc((size_t)nE * 4);
    int*   bsum = (int*)alloc(1024);
    float* accum = (float*)alloc(HID * 4);
    unsigned short* Wt_in = (unsigned short*)alloc(128 * 64 * 2);
    unsigned short* Wt_l  = (unsigned short*)alloc(3 * 128 * 128 * 2);

    hipMemsetAsync(cnt, 0, (size_t)n * 4, stream);
    hipMemsetAsync(accum, 0, HID * 4, stream);

    int egrid = (nE + 255) / 256;
    int nb = (n + 255) / 256;
    w_prep<<<(128 * 64 + 3 * 128 * 128 + 255) / 256, 256, 0, stream>>>(W_in, W_l, Wt_in, Wt_l);
    k_count<<<egrid, 256, 0, stream>>>(dst, nE, cnt);
    k_scan1<<<nb, 256, 0, stream>>>(cnt, n, rowp, bsum);
    k_scan2<<<1, 256, 0, stream>>>(bsum, nb);
    k_scan3<<<nb, 256, 0, stream>>>(rowp, bsum, cnt, n, nE, curs, invd);
    k_fill<<<egrid, 256, 0, stream>>>(src, dst, nE, curs, csrc);

    int tgrid = (n + RT - 1) / RT;
    k_inproj<<<tgrid, 256, 0, stream>>>(x, Wt_in, b_in, hbA, n);

    const unsigned* hin = hbA;
    unsigned* hout = hbB;
    for (int l = 0; l < 3; ++l) {
        k_layer<<<tgrid, 256, 0, stream>>>(hin, hout, rowp, csrc, invd,
                                           Wt_l + (size_t)l * 128 * 128,
                                           b_l + l * HID, lng + l * HID, lnb + l * HID, n);
        const unsigned* t = hout;
        hout = (unsigned*)hin;
        hin = t;
    }
    // after 3 swaps, final state is in `hin`
    k_rowsum<<<(n + 255) / 256, 64, 0, stream>>>(hin, nact, accum, n);
    k_out<<<1, HID, 0, stream>>>(accum, nact, W_o, b_o, (float*)d_out);
}

// Round 5
// 384.469 us; speedup vs baseline: 1.1862x; 1.1862x over previous
//
#include <hip/hip_runtime.h>

#define HID 128
#define INP 64
#define LN_EPS 1e-5f
#define RT 64   // rows per block in GEMM kernels

typedef __attribute__((ext_vector_type(8))) short bf16x8;
typedef __attribute__((ext_vector_type(4))) float f32x4;

__device__ __forceinline__ unsigned f2bf(float f) {
    unsigned u = __float_as_uint(f);
    return (u + 0x7FFFu + ((u >> 16) & 1u)) >> 16;   // RNE
}
__device__ __forceinline__ float bflo(unsigned v) { return __uint_as_float(v << 16); }
__device__ __forceinline__ float bfhi(unsigned v) { return __uint_as_float(v & 0xFFFF0000u); }

// ---------------- CSR build ----------------
__global__ void k_count(const int* __restrict__ dst, int nE, int* __restrict__ cnt) {
    int e = blockIdx.x * blockDim.x + threadIdx.x;
    if (e < nE) atomicAdd(&cnt[dst[e]], 1);
}

__global__ void k_scan1(const int* __restrict__ cnt, int n, int* __restrict__ rowp, int* __restrict__ bsum) {
    __shared__ int s[256];
    int i = blockIdx.x * 256 + threadIdx.x;
    int v = (i < n) ? cnt[i] : 0;
    s[threadIdx.x] = v;
    __syncthreads();
    for (int off = 1; off < 256; off <<= 1) {
        int t = (threadIdx.x >= off) ? s[threadIdx.x - off] : 0;
        __syncthreads();
        s[threadIdx.x] += t;
        __syncthreads();
    }
    if (i < n) rowp[i] = s[threadIdx.x] - v;  // exclusive
    if (threadIdx.x == 255) bsum[blockIdx.x] = s[255];
}

__global__ void k_scan2(int* __restrict__ bsum, int nb) {
    __shared__ int s[256];
    int v = (threadIdx.x < nb) ? bsum[threadIdx.x] : 0;
    s[threadIdx.x] = v;
    __syncthreads();
    for (int off = 1; off < 256; off <<= 1) {
        int t = (threadIdx.x >= off) ? s[threadIdx.x - off] : 0;
        __syncthreads();
        s[threadIdx.x] += t;
        __syncthreads();
    }
    if (threadIdx.x < nb) bsum[threadIdx.x] = s[threadIdx.x] - v;
}

__global__ void k_scan3(int* __restrict__ rowp, const int* __restrict__ bsum, const int* __restrict__ cnt,
                        int n, int nE, int* __restrict__ cursor, float* __restrict__ invd) {
    int i = blockIdx.x * 256 + threadIdx.x;
    if (i < n) {
        int rp = rowp[i] + bsum[blockIdx.x];
        rowp[i] = rp;
        cursor[i] = rp;
        int c = cnt[i];
        invd[i] = 1.0f / (float)(c > 1 ? c : 1);
    } else if (i == n) {
        rowp[n] = nE;
    }
}

__global__ void k_fill(const int* __restrict__ src, const int* __restrict__ dst, int nE,
                       int* __restrict__ cursor, int* __restrict__ csrc) {
    int e = blockIdx.x * blockDim.x + threadIdx.x;
    if (e < nE) {
        int p = atomicAdd(&cursor[dst[e]], 1);
        csrc[p] = src[e];
    }
}

// ---------------- weight prep: transpose + bf16 convert ----------------
__global__ void w_prep(const float* __restrict__ W_in, const float* __restrict__ W_l,
                       unsigned short* __restrict__ Wt_in, unsigned short* __restrict__ Wt_l) {
    int i = blockIdx.x * 256 + threadIdx.x;
    if (i < 128 * 64) {
        int col = i >> 6, k = i & 63;
        Wt_in[i] = (unsigned short)f2bf(W_in[(size_t)k * HID + col]);
    }
    int j = i - 128 * 64;
    if (j >= 0 && j < 3 * 128 * 128) {
        int l = j >> 14, r = j & 16383;
        int col = r >> 7, k = r & 127;
        Wt_l[j] = (unsigned short)f2bf(W_l[(size_t)l * 16384 + (size_t)k * HID + col]);
    }
}

// ---------------- in-projection (MFMA): hb = bf16(x @ W_in + b_in) ----------------
__global__ __launch_bounds__(256) void k_inproj(const float* __restrict__ x,
                                                const unsigned short* __restrict__ Wt,  // [128][64] bf16
                                                const float* __restrict__ b,
                                                unsigned* __restrict__ hout, int n) {
    __shared__ unsigned short xs[RT * INP];  // 8 KB, swizzled
    const int tid = threadIdx.x;
    const int row0 = blockIdx.x * RT;

#pragma unroll
    for (int j = 0; j < 2; ++j) {
        int fid = tid + j * 256;
        int r = fid >> 3, c = fid & 7;
        int grow = row0 + r;
        unsigned o[4] = {0, 0, 0, 0};
        if (grow < n) {
            float4 v0 = *reinterpret_cast<const float4*>(x + (size_t)grow * INP + c * 8);
            float4 v1 = *reinterpret_cast<const float4*>(x + (size_t)grow * INP + c * 8 + 4);
            o[0] = f2bf(v0.x) | (f2bf(v0.y) << 16);
            o[1] = f2bf(v0.z) | (f2bf(v0.w) << 16);
            o[2] = f2bf(v1.x) | (f2bf(v1.y) << 16);
            o[3] = f2bf(v1.z) | (f2bf(v1.w) << 16);
        }
        int sw = c ^ (r & 7);
        *reinterpret_cast<uint4*>(xs + r * INP + sw * 8) = make_uint4(o[0], o[1], o[2], o[3]);
    }
    __syncthreads();

    const int l = tid & 63;
    const int w = tid >> 6;
    const int l15 = l & 15, lg = l >> 4;
    const int xrow = w * 16 + l15;

    f32x4 acc[8];
#pragma unroll
    for (int t = 0; t < 8; ++t) acc[t] = (f32x4){0.f, 0.f, 0.f, 0.f};

#pragma unroll
    for (int kc = 0; kc < 2; ++kc) {
        int bc = (kc * 4 + lg) ^ (xrow & 7);
        bf16x8 bfrag = *reinterpret_cast<const bf16x8*>(xs + xrow * INP + bc * 8);
        const unsigned short* wp = Wt + (size_t)l15 * INP + kc * 32 + lg * 8;
        bf16x8 af[8];
#pragma unroll
        for (int t = 0; t < 8; ++t) af[t] = *reinterpret_cast<const bf16x8*>(wp + (size_t)t * 16 * INP);
#pragma unroll
        for (int t = 0; t < 8; ++t)
            acc[t] = __builtin_amdgcn_mfma_f32_16x16x32_bf16(af[t], bfrag, acc[t], 0, 0, 0);
    }

    int grow = row0 + xrow;
    if (grow < n) {
#pragma unroll
        for (int t = 0; t < 8; ++t) {
            int c0 = t * 16 + lg * 4;
            f32x4 bb = *reinterpret_cast<const f32x4*>(b + c0);
            f32x4 o = acc[t] + bb;
            uint2 p;
            p.x = f2bf(o.x) | (f2bf(o.y) << 16);
            p.y = f2bf(o.z) | (f2bf(o.w) << 16);
            *reinterpret_cast<uint2*>(hout + (size_t)grow * 64 + t * 8 + lg * 2) = p;
        }
    }
}

// ---------------- aggregation: aggx[v] = bf16( hb[v] + (sum_{u in N(v)} hb[u]) * invd[v] ), PRE-SWIZZLED ----------------
// one wave per node, one bf16 pair (uint) per lane, 8-edge unroll
__global__ __launch_bounds__(256) void k_agg(const unsigned* __restrict__ hb, const int* __restrict__ rowp,
                                             const int* __restrict__ csrc, const float* __restrict__ invd,
                                             unsigned* __restrict__ aggx, int n) {
    int node = blockIdx.x * 4 + (threadIdx.x >> 6);
    if (node >= n) return;
    int lane = threadIdx.x & 63;
    int e0 = rowp[node], e1 = rowp[node + 1];
    float ax = 0.f, ay = 0.f;
    int e = e0;
    for (; e + 8 <= e1; e += 8) {
        int s0 = csrc[e],     s1 = csrc[e + 1], s2 = csrc[e + 2], s3 = csrc[e + 3];
        int s4 = csrc[e + 4], s5 = csrc[e + 5], s6 = csrc[e + 6], s7 = csrc[e + 7];
        unsigned v0 = hb[(size_t)s0 * 64 + lane];
        unsigned v1 = hb[(size_t)s1 * 64 + lane];
        unsigned v2 = hb[(size_t)s2 * 64 + lane];
        unsigned v3 = hb[(size_t)s3 * 64 + lane];
        unsigned v4 = hb[(size_t)s4 * 64 + lane];
        unsigned v5 = hb[(size_t)s5 * 64 + lane];
        unsigned v6 = hb[(size_t)s6 * 64 + lane];
        unsigned v7 = hb[(size_t)s7 * 64 + lane];
        ax += ((bflo(v0) + bflo(v1)) + (bflo(v2) + bflo(v3))) +
              ((bflo(v4) + bflo(v5)) + (bflo(v6) + bflo(v7)));
        ay += ((bfhi(v0) + bfhi(v1)) + (bfhi(v2) + bfhi(v3))) +
              ((bfhi(v4) + bfhi(v5)) + (bfhi(v6) + bfhi(v7)));
    }
    for (; e < e1; ++e) {
        unsigned v = hb[(size_t)csrc[e] * 64 + lane];
        ax += bflo(v);
        ay += bfhi(v);
    }
    float inv = invd[node];
    unsigned self = hb[(size_t)node * 64 + lane];
    float xlo = bflo(self) + ax * inv;
    float xhi = bfhi(self) + ay * inv;
    unsigned o = f2bf(xlo) | (f2bf(xhi) << 16);
    // swizzled position: 16B chunk c -> c ^ (row&7), within the same 256B row
    int c = lane >> 2;
    int sw = c ^ (node & 7);
    aggx[(size_t)node * 64 + sw * 4 + (lane & 3)] = o;
}

// ---------------- layer MFMA: hout = relu(LN(X@W + b)*g + lnb) + hin,  X = aggx (pre-swizzled) ----------------
__global__ __launch_bounds__(256) void k_layer(const unsigned* __restrict__ hin,   // residual, [n*64] bf16 pairs
                                               unsigned* __restrict__ hout,
                                               const unsigned* __restrict__ aggx,  // pre-swizzled X
                                               const unsigned short* __restrict__ Wt,  // [128][128] bf16
                                               const float* __restrict__ bias, const float* __restrict__ g,
                                               const float* __restrict__ lnb, int n) {
    __shared__ unsigned short xs[RT * HID];  // 16 KB, already swizzled in global
    const int tid = threadIdx.x;
    const int row0 = blockIdx.x * RT;

    // stage: pure linear copy of 64 rows x 256B
    {
        const uint4* sp = reinterpret_cast<const uint4*>(aggx + (size_t)row0 * 64);
        uint4* dp = reinterpret_cast<uint4*>(xs);
#pragma unroll
        for (int j = 0; j < 4; ++j) dp[tid + j * 256] = sp[tid + j * 256];
    }
    __syncthreads();

    const int lane = tid & 63;
    const int w = tid >> 6;
    const int l15 = lane & 15, lg = lane >> 4;
    const int xrow = w * 16 + l15;

    f32x4 acc[8];
#pragma unroll
    for (int t = 0; t < 8; ++t) acc[t] = (f32x4){0.f, 0.f, 0.f, 0.f};

#pragma unroll
    for (int kc = 0; kc < 4; ++kc) {
        int bc = (kc * 4 + lg) ^ (xrow & 7);
        bf16x8 bfrag = *reinterpret_cast<const bf16x8*>(xs + xrow * HID + bc * 8);
        const unsigned short* wp = Wt + (size_t)l15 * HID + kc * 32 + lg * 8;
        bf16x8 af[8];
#pragma unroll
        for (int t = 0; t < 8; ++t) af[t] = *reinterpret_cast<const bf16x8*>(wp + (size_t)t * 16 * HID);
#pragma unroll
        for (int t = 0; t < 8; ++t)
            acc[t] = __builtin_amdgcn_mfma_f32_16x16x32_bf16(af[t], bfrag, acc[t], 0, 0, 0);
    }

    float s = 0.f, q = 0.f;
#pragma unroll
    for (int t = 0; t < 8; ++t) {
        int c0 = t * 16 + lg * 4;
        f32x4 bb = *reinterpret_cast<const f32x4*>(bias + c0);
        acc[t] = acc[t] + bb;
        s += acc[t].x + acc[t].y + acc[t].z + acc[t].w;
        q += acc[t].x * acc[t].x + acc[t].y * acc[t].y + acc[t].z * acc[t].z + acc[t].w * acc[t].w;
    }
    s += __shfl_xor(s, 16, 64);
    s += __shfl_xor(s, 32, 64);
    q += __shfl_xor(q, 16, 64);
    q += __shfl_xor(q, 32, 64);
    float mu = s * (1.0f / HID);
    float var = q * (1.0f / HID) - mu * mu;
    float rs = rsqrtf(var + LN_EPS);

    int grow = row0 + xrow;
    if (grow < n) {
#pragma unroll
        for (int t = 0; t < 8; ++t) {
            int c0 = t * 16 + lg * 4;
            uint2 rv = *reinterpret_cast<const uint2*>(hin + (size_t)grow * 64 + t * 8 + lg * 2);
            f32x4 gv = *reinterpret_cast<const f32x4*>(g + c0);
            f32x4 lb = *reinterpret_cast<const f32x4*>(lnb + c0);
            float o0 = fmaxf((acc[t].x - mu) * rs * gv.x + lb.x, 0.f) + bflo(rv.x);
            float o1 = fmaxf((acc[t].y - mu) * rs * gv.y + lb.y, 0.f) + bfhi(rv.x);
            float o2 = fmaxf((acc[t].z - mu) * rs * gv.z + lb.z, 0.f) + bflo(rv.y);
            float o3 = fmaxf((acc[t].w - mu) * rs * gv.w + lb.w, 0.f) + bfhi(rv.y);
            uint2 p;
            p.x = f2bf(o0) | (f2bf(o1) << 16);
            p.y = f2bf(o2) | (f2bf(o3) << 16);
            *reinterpret_cast<uint2*>(hout + (size_t)grow * 64 + t * 8 + lg * 2) = p;
        }
    }
}

// ---------------- final: accum[c] = sum over rows < n_act of h[r][c] ----------------
__global__ void k_rowsum(const unsigned* __restrict__ hb, const int* __restrict__ n_act_p,
                         float* __restrict__ accum, int n) {
    int na = *n_act_p;
    int row0 = blockIdx.x * 256;
    int c = threadIdx.x;  // 0..63, col pair
    int rend = row0 + 256;
    if (rend > na) rend = na;
    float sx = 0.f, sy = 0.f;
    for (int r = row0; r < rend; ++r) {
        unsigned v = hb[(size_t)r * 64 + c];
        sx += bflo(v);
        sy += bfhi(v);
    }
    if (row0 < na) {
        atomicAdd(&accum[2 * c], sx);
        atomicAdd(&accum[2 * c + 1], sy);
    }
}

__global__ void k_out(const float* __restrict__ accum, const int* __restrict__ n_act_p,
                      const float* __restrict__ W_out, const float* __restrict__ b_out,
                      float* __restrict__ out) {
    __shared__ float m[HID];
    int c = threadIdx.x;
    float na = (float)(*n_act_p);
    m[c] = accum[c] / na;
    __syncthreads();
    float s = b_out[c];
    for (int k = 0; k < HID; ++k) s += m[k] * W_out[k * HID + c];
    out[c] = s;
}

extern "C" void kernel_launch(void* const* d_in, const int* in_sizes, int n_in,
                              void* d_out, int out_size, void* d_ws, size_t ws_size,
                              hipStream_t stream) {
    const int n  = in_sizes[0] / INP;   // 50000
    const int nE = in_sizes[1] / 2;     // 800000
    const float* x    = (const float*)d_in[0];
    const int*   ei   = (const int*)d_in[1];
    const int*   src  = ei;
    const int*   dst  = ei + nE;
    const int*   nact = (const int*)d_in[2];
    const float* W_in = (const float*)d_in[3];
    const float* b_in = (const float*)d_in[4];
    const float* W_l  = (const float*)d_in[5];
    const float* b_l  = (const float*)d_in[6];
    const float* lng  = (const float*)d_in[7];
    const float* lnb  = (const float*)d_in[8];
    const float* W_o  = (const float*)d_in[9];
    const float* b_o  = (const float*)d_in[10];

    char* ws = (char*)d_ws;
    size_t off = 0;
    auto alloc = [&](size_t bytes) {
        void* p = ws + off;
        off = (off + bytes + 255) & ~((size_t)255);
        return p;
    };
    unsigned* hbA  = (unsigned*)alloc((size_t)n * 64 * 4);
    unsigned* hbB  = (unsigned*)alloc((size_t)n * 64 * 4);
    unsigned* aggx = (unsigned*)alloc((size_t)(n + RT) * 64 * 4);  // +RT rows pad for tail-block staging reads
    int*   cnt  = (int*)alloc((size_t)n * 4);
    int*   rowp = (int*)alloc((size_t)(n + 1) * 4);
    int*   curs = (int*)alloc((size_t)n * 4);
    float* invd = (float*)alloc((size_t)n * 4);
    int*   csrc = (int*)alloc((size_t)nE * 4);
    int*   bsum = (int*)alloc(1024);
    float* accum = (float*)alloc(HID * 4);
    unsigned short* Wt_in = (unsigned short*)alloc(128 * 64 * 2);
    unsigned short* Wt_l  = (unsigned short*)alloc(3 * 128 * 128 * 2);

    hipMemsetAsync(cnt, 0, (size_t)n * 4, stream);
    hipMemsetAsync(accum, 0, HID * 4, stream);

    int egrid = (nE + 255) / 256;
    int nb = (n + 255) / 256;
    w_prep<<<(128 * 64 + 3 * 128 * 128 + 255) / 256, 256, 0, stream>>>(W_in, W_l, Wt_in, Wt_l);
    k_count<<<egrid, 256, 0, stream>>>(dst, nE, cnt);
    k_scan1<<<nb, 256, 0, stream>>>(cnt, n, rowp, bsum);
    k_scan2<<<1, 256, 0, stream>>>(bsum, nb);
    k_scan3<<<nb, 256, 0, stream>>>(rowp, bsum, cnt, n, nE, curs, invd);
    k_fill<<<egrid, 256, 0, stream>>>(src, dst, nE, curs, csrc);

    int tgrid = (n + RT - 1) / RT;
    k_inproj<<<tgrid, 256, 0, stream>>>(x, Wt_in, b_in, hbA, n);

    const unsigned* hin = hbA;
    unsigned* hout = hbB;
    for (int l = 0; l < 3; ++l) {
        k_agg<<<(n + 3) / 4, 256, 0, stream>>>(hin, rowp, csrc, invd, aggx, n);
        k_layer<<<tgrid, 256, 0, stream>>>(hin, hout, aggx,
                                           Wt_l + (size_t)l * 128 * 128,
                                           b_l + l * HID, lng + l * HID, lnb + l * HID, n);
        const unsigned* t = hout;
        hout = (unsigned*)hin;
        hin = t;
    }
    k_rowsum<<<(n + 255) / 256, 64, 0, stream>>>(hin, nact, accum, n);
    k_out<<<1, HID, 0, stream>>>(accum, nact, W_o, b_o, (float*)d_out);
}

// Round 6
// 339.575 us; speedup vs baseline: 1.3430x; 1.1322x over previous
//
#include <hip/hip_runtime.h>

#define HID 128
#define INP 64
#define LN_EPS 1e-5f
#define RT 64   // rows per block in GEMM kernels

typedef __attribute__((ext_vector_type(8))) short bf16x8;
typedef __attribute__((ext_vector_type(4))) float f32x4;

__device__ __forceinline__ unsigned f2bf(float f) {
    unsigned u = __float_as_uint(f);
    return (u + 0x7FFFu + ((u >> 16) & 1u)) >> 16;   // RNE
}
__device__ __forceinline__ float bflo(unsigned v) { return __uint_as_float(v << 16); }
__device__ __forceinline__ float bfhi(unsigned v) { return __uint_as_float(v & 0xFFFF0000u); }

// ---------------- CSR build ----------------
__global__ void k_count(const int* __restrict__ dst, int nE, int* __restrict__ cnt) {
    int e = blockIdx.x * blockDim.x + threadIdx.x;
    if (e < nE) atomicAdd(&cnt[dst[e]], 1);
}

__global__ void k_scan1(const int* __restrict__ cnt, int n, int* __restrict__ rowp, int* __restrict__ bsum) {
    __shared__ int s[256];
    int i = blockIdx.x * 256 + threadIdx.x;
    int v = (i < n) ? cnt[i] : 0;
    s[threadIdx.x] = v;
    __syncthreads();
    for (int off = 1; off < 256; off <<= 1) {
        int t = (threadIdx.x >= off) ? s[threadIdx.x - off] : 0;
        __syncthreads();
        s[threadIdx.x] += t;
        __syncthreads();
    }
    if (i < n) rowp[i] = s[threadIdx.x] - v;  // exclusive
    if (threadIdx.x == 255) bsum[blockIdx.x] = s[255];
}

__global__ void k_scan2(int* __restrict__ bsum, int nb) {
    __shared__ int s[256];
    int v = (threadIdx.x < nb) ? bsum[threadIdx.x] : 0;
    s[threadIdx.x] = v;
    __syncthreads();
    for (int off = 1; off < 256; off <<= 1) {
        int t = (threadIdx.x >= off) ? s[threadIdx.x - off] : 0;
        __syncthreads();
        s[threadIdx.x] += t;
        __syncthreads();
    }
    if (threadIdx.x < nb) bsum[threadIdx.x] = s[threadIdx.x] - v;
}

__global__ void k_scan3(int* __restrict__ rowp, const int* __restrict__ bsum, const int* __restrict__ cnt,
                        int n, int nE, int* __restrict__ cursor, float* __restrict__ invd) {
    int i = blockIdx.x * 256 + threadIdx.x;
    if (i < n) {
        int rp = rowp[i] + bsum[blockIdx.x];
        rowp[i] = rp;
        cursor[i] = rp;
        int c = cnt[i];
        invd[i] = 1.0f / (float)(c > 1 ? c : 1);
    } else if (i == n) {
        rowp[n] = nE;
    }
}

__global__ void k_fill(const int* __restrict__ src, const int* __restrict__ dst, int nE,
                       int* __restrict__ cursor, int* __restrict__ csrc) {
    int e = blockIdx.x * blockDim.x + threadIdx.x;
    if (e < nE) {
        int p = atomicAdd(&cursor[dst[e]], 1);
        csrc[p] = src[e];
    }
}

// ---------------- weight prep: transpose + bf16 convert ----------------
__global__ void w_prep(const float* __restrict__ W_in, const float* __restrict__ W_l,
                       unsigned short* __restrict__ Wt_in, unsigned short* __restrict__ Wt_l) {
    int i = blockIdx.x * 256 + threadIdx.x;
    if (i < 128 * 64) {
        int col = i >> 6, k = i & 63;
        Wt_in[i] = (unsigned short)f2bf(W_in[(size_t)k * HID + col]);
    }
    int j = i - 128 * 64;
    if (j >= 0 && j < 3 * 128 * 128) {
        int l = j >> 14, r = j & 16383;
        int col = r >> 7, k = r & 127;
        Wt_l[j] = (unsigned short)f2bf(W_l[(size_t)l * 16384 + (size_t)k * HID + col]);
    }
}

// ---------------- in-projection (MFMA): hb = bf16(x @ W_in + b_in) ----------------
__global__ __launch_bounds__(256) void k_inproj(const float* __restrict__ x,
                                                const unsigned short* __restrict__ Wt,  // [128][64] bf16
                                                const float* __restrict__ b,
                                                unsigned* __restrict__ hout, int n) {
    __shared__ unsigned short xs[RT * INP];  // 8 KB, swizzled
    const int tid = threadIdx.x;
    const int row0 = blockIdx.x * RT;

#pragma unroll
    for (int j = 0; j < 2; ++j) {
        int fid = tid + j * 256;
        int r = fid >> 3, c = fid & 7;
        int grow = row0 + r;
        unsigned o[4] = {0, 0, 0, 0};
        if (grow < n) {
            float4 v0 = *reinterpret_cast<const float4*>(x + (size_t)grow * INP + c * 8);
            float4 v1 = *reinterpret_cast<const float4*>(x + (size_t)grow * INP + c * 8 + 4);
            o[0] = f2bf(v0.x) | (f2bf(v0.y) << 16);
            o[1] = f2bf(v0.z) | (f2bf(v0.w) << 16);
            o[2] = f2bf(v1.x) | (f2bf(v1.y) << 16);
            o[3] = f2bf(v1.z) | (f2bf(v1.w) << 16);
        }
        int sw = c ^ (r & 7);
        *reinterpret_cast<uint4*>(xs + r * INP + sw * 8) = make_uint4(o[0], o[1], o[2], o[3]);
    }
    __syncthreads();

    const int l = tid & 63;
    const int w = tid >> 6;
    const int l15 = l & 15, lg = l >> 4;
    const int xrow = w * 16 + l15;

    f32x4 acc[8];
#pragma unroll
    for (int t = 0; t < 8; ++t) acc[t] = (f32x4){0.f, 0.f, 0.f, 0.f};

#pragma unroll
    for (int kc = 0; kc < 2; ++kc) {
        int bc = (kc * 4 + lg) ^ (xrow & 7);
        bf16x8 bfrag = *reinterpret_cast<const bf16x8*>(xs + xrow * INP + bc * 8);
        const unsigned short* wp = Wt + (size_t)l15 * INP + kc * 32 + lg * 8;
        bf16x8 af[8];
#pragma unroll
        for (int t = 0; t < 8; ++t) af[t] = *reinterpret_cast<const bf16x8*>(wp + (size_t)t * 16 * INP);
#pragma unroll
        for (int t = 0; t < 8; ++t)
            acc[t] = __builtin_amdgcn_mfma_f32_16x16x32_bf16(af[t], bfrag, acc[t], 0, 0, 0);
    }

    int grow = row0 + xrow;
    if (grow < n) {
#pragma unroll
        for (int t = 0; t < 8; ++t) {
            int c0 = t * 16 + lg * 4;
            f32x4 bb = *reinterpret_cast<const f32x4*>(b + c0);
            f32x4 o = acc[t] + bb;
            uint2 p;
            p.x = f2bf(o.x) | (f2bf(o.y) << 16);
            p.y = f2bf(o.z) | (f2bf(o.w) << 16);
            *reinterpret_cast<uint2*>(hout + (size_t)grow * 64 + t * 8 + lg * 2) = p;
        }
    }
}

// ---------------- aggregation: aggx[v] = bf16( hb[v] + (sum_{u in N(v)} hb[u]) * invd[v] ), PRE-SWIZZLED ----------------
__global__ __launch_bounds__(256) void k_agg(const unsigned* __restrict__ hb, const int* __restrict__ rowp,
                                             const int* __restrict__ csrc, const float* __restrict__ invd,
                                             unsigned* __restrict__ aggx, int n) {
    int node = blockIdx.x * 4 + (threadIdx.x >> 6);
    if (node >= n) return;
    int lane = threadIdx.x & 63;
    int e0 = rowp[node], e1 = rowp[node + 1];
    float ax = 0.f, ay = 0.f;
    int e = e0;
    for (; e + 8 <= e1; e += 8) {
        int s0 = csrc[e],     s1 = csrc[e + 1], s2 = csrc[e + 2], s3 = csrc[e + 3];
        int s4 = csrc[e + 4], s5 = csrc[e + 5], s6 = csrc[e + 6], s7 = csrc[e + 7];
        unsigned v0 = hb[(size_t)s0 * 64 + lane];
        unsigned v1 = hb[(size_t)s1 * 64 + lane];
        unsigned v2 = hb[(size_t)s2 * 64 + lane];
        unsigned v3 = hb[(size_t)s3 * 64 + lane];
        unsigned v4 = hb[(size_t)s4 * 64 + lane];
        unsigned v5 = hb[(size_t)s5 * 64 + lane];
        unsigned v6 = hb[(size_t)s6 * 64 + lane];
        unsigned v7 = hb[(size_t)s7 * 64 + lane];
        ax += ((bflo(v0) + bflo(v1)) + (bflo(v2) + bflo(v3))) +
              ((bflo(v4) + bflo(v5)) + (bflo(v6) + bflo(v7)));
        ay += ((bfhi(v0) + bfhi(v1)) + (bfhi(v2) + bfhi(v3))) +
              ((bfhi(v4) + bfhi(v5)) + (bfhi(v6) + bfhi(v7)));
    }
    for (; e < e1; ++e) {
        unsigned v = hb[(size_t)csrc[e] * 64 + lane];
        ax += bflo(v);
        ay += bfhi(v);
    }
    float inv = invd[node];
    unsigned self = hb[(size_t)node * 64 + lane];
    float xlo = bflo(self) + ax * inv;
    float xhi = bfhi(self) + ay * inv;
    unsigned o = f2bf(xlo) | (f2bf(xhi) << 16);
    // swizzled position: 16B chunk c -> c ^ (row&7), within the same 256B row
    int c = lane >> 2;
    int sw = c ^ (node & 7);
    aggx[(size_t)node * 64 + sw * 4 + (lane & 3)] = o;
}

// ---------------- layer MFMA (no LDS): hout = relu(LN(X@W + b)*g + lnb) + hin ----------------
// X fragments loaded DIRECTLY from pre-swizzled global aggx
__global__ __launch_bounds__(256) void k_layer(const unsigned* __restrict__ hin,   // residual, [n*64] bf16 pairs
                                               unsigned* __restrict__ hout,
                                               const unsigned* __restrict__ aggx,  // pre-swizzled X (padded)
                                               const unsigned short* __restrict__ Wt,  // [128][128] bf16
                                               const float* __restrict__ bias, const float* __restrict__ g,
                                               const float* __restrict__ lnb, int n) {
    const int tid = threadIdx.x;
    const int row0 = blockIdx.x * RT;
    const int lane = tid & 63;
    const int w = tid >> 6;
    const int l15 = lane & 15, lg = lane >> 4;
    const int xrow = w * 16 + l15;
    const int grow = row0 + xrow;   // may be >= n for tail block; aggx is padded

    const unsigned short* xg = reinterpret_cast<const unsigned short*>(aggx) + (size_t)grow * HID;

    f32x4 acc[8];
#pragma unroll
    for (int t = 0; t < 8; ++t) acc[t] = (f32x4){0.f, 0.f, 0.f, 0.f};

#pragma unroll
    for (int kc = 0; kc < 4; ++kc) {
        int bc = (kc * 4 + lg) ^ (xrow & 7);
        bf16x8 bfrag = *reinterpret_cast<const bf16x8*>(xg + bc * 8);
        const unsigned short* wp = Wt + (size_t)l15 * HID + kc * 32 + lg * 8;
        bf16x8 af[8];
#pragma unroll
        for (int t = 0; t < 8; ++t) af[t] = *reinterpret_cast<const bf16x8*>(wp + (size_t)t * 16 * HID);
#pragma unroll
        for (int t = 0; t < 8; ++t)
            acc[t] = __builtin_amdgcn_mfma_f32_16x16x32_bf16(af[t], bfrag, acc[t], 0, 0, 0);
    }

    float s = 0.f, q = 0.f;
#pragma unroll
    for (int t = 0; t < 8; ++t) {
        int c0 = t * 16 + lg * 4;
        f32x4 bb = *reinterpret_cast<const f32x4*>(bias + c0);
        acc[t] = acc[t] + bb;
        s += acc[t].x + acc[t].y + acc[t].z + acc[t].w;
        q += acc[t].x * acc[t].x + acc[t].y * acc[t].y + acc[t].z * acc[t].z + acc[t].w * acc[t].w;
    }
    s += __shfl_xor(s, 16, 64);
    s += __shfl_xor(s, 32, 64);
    q += __shfl_xor(q, 16, 64);
    q += __shfl_xor(q, 32, 64);
    float mu = s * (1.0f / HID);
    float var = q * (1.0f / HID) - mu * mu;
    float rs = rsqrtf(var + LN_EPS);

    if (grow < n) {
#pragma unroll
        for (int t = 0; t < 8; ++t) {
            int c0 = t * 16 + lg * 4;
            uint2 rv = *reinterpret_cast<const uint2*>(hin + (size_t)grow * 64 + t * 8 + lg * 2);
            f32x4 gv = *reinterpret_cast<const f32x4*>(g + c0);
            f32x4 lb = *reinterpret_cast<const f32x4*>(lnb + c0);
            float o0 = fmaxf((acc[t].x - mu) * rs * gv.x + lb.x, 0.f) + bflo(rv.x);
            float o1 = fmaxf((acc[t].y - mu) * rs * gv.y + lb.y, 0.f) + bfhi(rv.x);
            float o2 = fmaxf((acc[t].z - mu) * rs * gv.z + lb.z, 0.f) + bflo(rv.y);
            float o3 = fmaxf((acc[t].w - mu) * rs * gv.w + lb.w, 0.f) + bfhi(rv.y);
            uint2 p;
            p.x = f2bf(o0) | (f2bf(o1) << 16);
            p.y = f2bf(o2) | (f2bf(o3) << 16);
            *reinterpret_cast<uint2*>(hout + (size_t)grow * 64 + t * 8 + lg * 2) = p;
        }
    }
}

// ---------------- final: accum[c] = sum over rows < n_act of h[r][c] ----------------
__global__ __launch_bounds__(256) void k_rowsum(const unsigned* __restrict__ hb, const int* __restrict__ n_act_p,
                                                float* __restrict__ accum, int n) {
    __shared__ float sred[256 * 2];
    int na = *n_act_p;
    int row0 = blockIdx.x * 256;
    int c = threadIdx.x & 63;    // col pair
    int sub = threadIdx.x >> 6;  // 0..3
    int rend = row0 + 256;
    if (rend > na) rend = na;
    float sx = 0.f, sy = 0.f;
    for (int r = row0 + sub; r < rend; r += 4) {
        unsigned v = hb[(size_t)r * 64 + c];
        sx += bflo(v);
        sy += bfhi(v);
    }
    sred[threadIdx.x * 2] = sx;
    sred[threadIdx.x * 2 + 1] = sy;
    __syncthreads();
    if (threadIdx.x < 64) {
        float tx = sred[threadIdx.x * 2] + sred[(threadIdx.x + 64) * 2] +
                   sred[(threadIdx.x + 128) * 2] + sred[(threadIdx.x + 192) * 2];
        float ty = sred[threadIdx.x * 2 + 1] + sred[(threadIdx.x + 64) * 2 + 1] +
                   sred[(threadIdx.x + 128) * 2 + 1] + sred[(threadIdx.x + 192) * 2 + 1];
        if (row0 < na) {
            atomicAdd(&accum[2 * threadIdx.x], tx);
            atomicAdd(&accum[2 * threadIdx.x + 1], ty);
        }
    }
}

__global__ void k_out(const float* __restrict__ accum, const int* __restrict__ n_act_p,
                      const float* __restrict__ W_out, const float* __restrict__ b_out,
                      float* __restrict__ out) {
    __shared__ float m[HID];
    int c = threadIdx.x;
    float na = (float)(*n_act_p);
    m[c] = accum[c] / na;
    __syncthreads();
    float s = b_out[c];
    for (int k = 0; k < HID; ++k) s += m[k] * W_out[k * HID + c];
    out[c] = s;
}

extern "C" void kernel_launch(void* const* d_in, const int* in_sizes, int n_in,
                              void* d_out, int out_size, void* d_ws, size_t ws_size,
                              hipStream_t stream) {
    const int n  = in_sizes[0] / INP;   // 50000
    const int nE = in_sizes[1] / 2;     // 800000
    const float* x    = (const float*)d_in[0];
    const int*   ei   = (const int*)d_in[1];
    const int*   src  = ei;
    const int*   dst  = ei + nE;
    const int*   nact = (const int*)d_in[2];
    const float* W_in = (const float*)d_in[3];
    const float* b_in = (const float*)d_in[4];
    const float* W_l  = (const float*)d_in[5];
    const float* b_l  = (const float*)d_in[6];
    const float* lng  = (const float*)d_in[7];
    const float* lnb  = (const float*)d_in[8];
    const float* W_o  = (const float*)d_in[9];
    const float* b_o  = (const float*)d_in[10];

    char* ws = (char*)d_ws;
    size_t off = 0;
    auto alloc = [&](size_t bytes) {
        void* p = ws + off;
        off = (off + bytes + 255) & ~((size_t)255);
        return p;
    };
    unsigned* hbA  = (unsigned*)alloc((size_t)n * 64 * 4);
    unsigned* hbB  = (unsigned*)alloc((size_t)n * 64 * 4);
    unsigned* aggx = (unsigned*)alloc((size_t)(n + RT) * 64 * 4);  // +RT rows pad for tail-block frag reads
    int*   cnt  = (int*)alloc((size_t)n * 4);
    int*   rowp = (int*)alloc((size_t)(n + 1) * 4);
    int*   curs = (int*)alloc((size_t)n * 4);
    float* invd = (float*)alloc((size_t)n * 4);
    int*   csrc = (int*)alloc((size_t)nE * 4);
    int*   bsum = (int*)alloc(1024);
    float* accum = (float*)alloc(HID * 4);
    unsigned short* Wt_in = (unsigned short*)alloc(128 * 64 * 2);
    unsigned short* Wt_l  = (unsigned short*)alloc(3 * 128 * 128 * 2);

    hipMemsetAsync(cnt, 0, (size_t)n * 4, stream);
    hipMemsetAsync(accum, 0, HID * 4, stream);

    int egrid = (nE + 255) / 256;
    int nb = (n + 255) / 256;
    w_prep<<<(128 * 64 + 3 * 128 * 128 + 255) / 256, 256, 0, stream>>>(W_in, W_l, Wt_in, Wt_l);
    k_count<<<egrid, 256, 0, stream>>>(dst, nE, cnt);
    k_scan1<<<nb, 256, 0, stream>>>(cnt, n, rowp, bsum);
    k_scan2<<<1, 256, 0, stream>>>(bsum, nb);
    k_scan3<<<nb, 256, 0, stream>>>(rowp, bsum, cnt, n, nE, curs, invd);
    k_fill<<<egrid, 256, 0, stream>>>(src, dst, nE, curs, csrc);

    int tgrid = (n + RT - 1) / RT;
    k_inproj<<<tgrid, 256, 0, stream>>>(x, Wt_in, b_in, hbA, n);

    const unsigned* hin = hbA;
    unsigned* hout = hbB;
    for (int l = 0; l < 3; ++l) {
        k_agg<<<(n + 3) / 4, 256, 0, stream>>>(hin, rowp, csrc, invd, aggx, n);
        k_layer<<<tgrid, 256, 0, stream>>>(hin, hout, aggx,
                                           Wt_l + (size_t)l * 128 * 128,
                                           b_l + l * HID, lng + l * HID, lnb + l * HID, n);
        const unsigned* t = hout;
        hout = (unsigned*)hin;
        hin = t;
    }
    k_rowsum<<<(n + 255) / 256, 256, 0, stream>>>(hin, nact, accum, n);
    k_out<<<1, HID, 0, stream>>>(accum, nact, W_o, b_o, (float*)d_out);
}

// Round 7
// 323.568 us; speedup vs baseline: 1.4095x; 1.0495x over previous
//
#include <hip/hip_runtime.h>

#define HID 128
#define INP 64
#define LN_EPS 1e-5f
#define RT 64   // rows per block in GEMM kernels

typedef __attribute__((ext_vector_type(8))) short bf16x8;
typedef __attribute__((ext_vector_type(4))) float f32x4;

__device__ __forceinline__ unsigned f2bf(float f) {
    unsigned u = __float_as_uint(f);
    return (u + 0x7FFFu + ((u >> 16) & 1u)) >> 16;   // RNE
}
__device__ __forceinline__ float bflo(unsigned v) { return __uint_as_float(v << 16); }
__device__ __forceinline__ float bfhi(unsigned v) { return __uint_as_float(v & 0xFFFF0000u); }

// ---------------- CSR build ----------------
// 8 edges/thread: fire-and-forget atomics, ILP
__global__ __launch_bounds__(256) void k_count(const int* __restrict__ dst, int nE, int* __restrict__ cnt) {
    int t = blockIdx.x * 256 + threadIdx.x;
    int base = t * 8;
    if (base + 8 <= nE) {
        int4 d0 = *reinterpret_cast<const int4*>(dst + base);
        int4 d1 = *reinterpret_cast<const int4*>(dst + base + 4);
        atomicAdd(&cnt[d0.x], 1);
        atomicAdd(&cnt[d0.y], 1);
        atomicAdd(&cnt[d0.z], 1);
        atomicAdd(&cnt[d0.w], 1);
        atomicAdd(&cnt[d1.x], 1);
        atomicAdd(&cnt[d1.y], 1);
        atomicAdd(&cnt[d1.z], 1);
        atomicAdd(&cnt[d1.w], 1);
    } else if (base < nE) {
        for (int e = base; e < nE; ++e) atomicAdd(&cnt[dst[e]], 1);
    }
}

__global__ void k_scan1(const int* __restrict__ cnt, int n, int* __restrict__ rowp, int* __restrict__ bsum) {
    __shared__ int s[256];
    int i = blockIdx.x * 256 + threadIdx.x;
    int v = (i < n) ? cnt[i] : 0;
    s[threadIdx.x] = v;
    __syncthreads();
    for (int off = 1; off < 256; off <<= 1) {
        int t = (threadIdx.x >= off) ? s[threadIdx.x - off] : 0;
        __syncthreads();
        s[threadIdx.x] += t;
        __syncthreads();
    }
    if (i < n) rowp[i] = s[threadIdx.x] - v;  // exclusive
    if (threadIdx.x == 255) bsum[blockIdx.x] = s[255];
}

__global__ void k_scan2(int* __restrict__ bsum, int nb) {
    __shared__ int s[256];
    int v = (threadIdx.x < nb) ? bsum[threadIdx.x] : 0;
    s[threadIdx.x] = v;
    __syncthreads();
    for (int off = 1; off < 256; off <<= 1) {
        int t = (threadIdx.x >= off) ? s[threadIdx.x - off] : 0;
        __syncthreads();
        s[threadIdx.x] += t;
        __syncthreads();
    }
    if (threadIdx.x < nb) bsum[threadIdx.x] = s[threadIdx.x] - v;
}

__global__ void k_scan3(int* __restrict__ rowp, const int* __restrict__ bsum, const int* __restrict__ cnt,
                        int n, int nE, int* __restrict__ cursor, float* __restrict__ invd) {
    int i = blockIdx.x * 256 + threadIdx.x;
    if (i < n) {
        int rp = rowp[i] + bsum[blockIdx.x];
        rowp[i] = rp;
        cursor[i] = rp;
        int c = cnt[i];
        invd[i] = 1.0f / (float)(c > 1 ? c : 1);
    } else if (i == n) {
        rowp[n] = nE;
    }
}

// 8 edges/thread: 8 pipelined atomic-returns, then 8 fire-and-forget scatter stores
__global__ __launch_bounds__(256) void k_fill(const int* __restrict__ src, const int* __restrict__ dst, int nE,
                                              int* __restrict__ cursor, int* __restrict__ csrc) {
    int t = blockIdx.x * 256 + threadIdx.x;
    int base = t * 8;
    if (base + 8 <= nE) {
        int4 d0 = *reinterpret_cast<const int4*>(dst + base);
        int4 d1 = *reinterpret_cast<const int4*>(dst + base + 4);
        int4 s0 = *reinterpret_cast<const int4*>(src + base);
        int4 s1 = *reinterpret_cast<const int4*>(src + base + 4);
        int p0 = atomicAdd(&cursor[d0.x], 1);
        int p1 = atomicAdd(&cursor[d0.y], 1);
        int p2 = atomicAdd(&cursor[d0.z], 1);
        int p3 = atomicAdd(&cursor[d0.w], 1);
        int p4 = atomicAdd(&cursor[d1.x], 1);
        int p5 = atomicAdd(&cursor[d1.y], 1);
        int p6 = atomicAdd(&cursor[d1.z], 1);
        int p7 = atomicAdd(&cursor[d1.w], 1);
        csrc[p0] = s0.x;
        csrc[p1] = s0.y;
        csrc[p2] = s0.z;
        csrc[p3] = s0.w;
        csrc[p4] = s1.x;
        csrc[p5] = s1.y;
        csrc[p6] = s1.z;
        csrc[p7] = s1.w;
    } else if (base < nE) {
        for (int e = base; e < nE; ++e) {
            int p = atomicAdd(&cursor[dst[e]], 1);
            csrc[p] = src[e];
        }
    }
}

// ---------------- weight prep: transpose + bf16 convert ----------------
__global__ void w_prep(const float* __restrict__ W_in, const float* __restrict__ W_l,
                       unsigned short* __restrict__ Wt_in, unsigned short* __restrict__ Wt_l) {
    int i = blockIdx.x * 256 + threadIdx.x;
    if (i < 128 * 64) {
        int col = i >> 6, k = i & 63;
        Wt_in[i] = (unsigned short)f2bf(W_in[(size_t)k * HID + col]);
    }
    int j = i - 128 * 64;
    if (j >= 0 && j < 3 * 128 * 128) {
        int l = j >> 14, r = j & 16383;
        int col = r >> 7, k = r & 127;
        Wt_l[j] = (unsigned short)f2bf(W_l[(size_t)l * 16384 + (size_t)k * HID + col]);
    }
}

// ---------------- in-projection (MFMA): hb = bf16(x @ W_in + b_in) ----------------
__global__ __launch_bounds__(256) void k_inproj(const float* __restrict__ x,
                                                const unsigned short* __restrict__ Wt,  // [128][64] bf16
                                                const float* __restrict__ b,
                                                unsigned* __restrict__ hout, int n) {
    __shared__ unsigned short xs[RT * INP];  // 8 KB, swizzled
    const int tid = threadIdx.x;
    const int row0 = blockIdx.x * RT;

#pragma unroll
    for (int j = 0; j < 2; ++j) {
        int fid = tid + j * 256;
        int r = fid >> 3, c = fid & 7;
        int grow = row0 + r;
        unsigned o[4] = {0, 0, 0, 0};
        if (grow < n) {
            float4 v0 = *reinterpret_cast<const float4*>(x + (size_t)grow * INP + c * 8);
            float4 v1 = *reinterpret_cast<const float4*>(x + (size_t)grow * INP + c * 8 + 4);
            o[0] = f2bf(v0.x) | (f2bf(v0.y) << 16);
            o[1] = f2bf(v0.z) | (f2bf(v0.w) << 16);
            o[2] = f2bf(v1.x) | (f2bf(v1.y) << 16);
            o[3] = f2bf(v1.z) | (f2bf(v1.w) << 16);
        }
        int sw = c ^ (r & 7);
        *reinterpret_cast<uint4*>(xs + r * INP + sw * 8) = make_uint4(o[0], o[1], o[2], o[3]);
    }
    __syncthreads();

    const int l = tid & 63;
    const int w = tid >> 6;
    const int l15 = l & 15, lg = l >> 4;
    const int xrow = w * 16 + l15;

    f32x4 acc[8];
#pragma unroll
    for (int t = 0; t < 8; ++t) acc[t] = (f32x4){0.f, 0.f, 0.f, 0.f};

#pragma unroll
    for (int kc = 0; kc < 2; ++kc) {
        int bc = (kc * 4 + lg) ^ (xrow & 7);
        bf16x8 bfrag = *reinterpret_cast<const bf16x8*>(xs + xrow * INP + bc * 8);
        const unsigned short* wp = Wt + (size_t)l15 * INP + kc * 32 + lg * 8;
        bf16x8 af[8];
#pragma unroll
        for (int t = 0; t < 8; ++t) af[t] = *reinterpret_cast<const bf16x8*>(wp + (size_t)t * 16 * INP);
#pragma unroll
        for (int t = 0; t < 8; ++t)
            acc[t] = __builtin_amdgcn_mfma_f32_16x16x32_bf16(af[t], bfrag, acc[t], 0, 0, 0);
    }

    int grow = row0 + xrow;
    if (grow < n) {
#pragma unroll
        for (int t = 0; t < 8; ++t) {
            int c0 = t * 16 + lg * 4;
            f32x4 bb = *reinterpret_cast<const f32x4*>(b + c0);
            f32x4 o = acc[t] + bb;
            uint2 p;
            p.x = f2bf(o.x) | (f2bf(o.y) << 16);
            p.y = f2bf(o.z) | (f2bf(o.w) << 16);
            *reinterpret_cast<uint2*>(hout + (size_t)grow * 64 + t * 8 + lg * 2) = p;
        }
    }
}

// ---------------- aggregation: aggx[v] = bf16( hb[v] + (sum_{u in N(v)} hb[u]) * invd[v] ), PRE-SWIZZLED ----------------
// grid-stride: one wave per node per iteration
__global__ __launch_bounds__(256) void k_agg(const unsigned* __restrict__ hb, const int* __restrict__ rowp,
                                             const int* __restrict__ csrc, const float* __restrict__ invd,
                                             unsigned* __restrict__ aggx, int n, int nwaves) {
    const int wave0 = (blockIdx.x * 256 + threadIdx.x) >> 6;
    const int lane = threadIdx.x & 63;
    for (int node = wave0; node < n; node += nwaves) {
        int e0 = rowp[node], e1 = rowp[node + 1];
        unsigned self = hb[(size_t)node * 64 + lane];
        float inv = invd[node];
        float ax = 0.f, ay = 0.f;
        int e = e0;
        for (; e + 8 <= e1; e += 8) {
            int s0 = csrc[e],     s1 = csrc[e + 1], s2 = csrc[e + 2], s3 = csrc[e + 3];
            int s4 = csrc[e + 4], s5 = csrc[e + 5], s6 = csrc[e + 6], s7 = csrc[e + 7];
            unsigned v0 = hb[(size_t)s0 * 64 + lane];
            unsigned v1 = hb[(size_t)s1 * 64 + lane];
            unsigned v2 = hb[(size_t)s2 * 64 + lane];
            unsigned v3 = hb[(size_t)s3 * 64 + lane];
            unsigned v4 = hb[(size_t)s4 * 64 + lane];
            unsigned v5 = hb[(size_t)s5 * 64 + lane];
            unsigned v6 = hb[(size_t)s6 * 64 + lane];
            unsigned v7 = hb[(size_t)s7 * 64 + lane];
            ax += ((bflo(v0) + bflo(v1)) + (bflo(v2) + bflo(v3))) +
                  ((bflo(v4) + bflo(v5)) + (bflo(v6) + bflo(v7)));
            ay += ((bfhi(v0) + bfhi(v1)) + (bfhi(v2) + bfhi(v3))) +
                  ((bfhi(v4) + bfhi(v5)) + (bfhi(v6) + bfhi(v7)));
        }
        for (; e < e1; ++e) {
            unsigned v = hb[(size_t)csrc[e] * 64 + lane];
            ax += bflo(v);
            ay += bfhi(v);
        }
        float xlo = bflo(self) + ax * inv;
        float xhi = bfhi(self) + ay * inv;
        unsigned o = f2bf(xlo) | (f2bf(xhi) << 16);
        // swizzled position: 16B chunk c -> c ^ (row&7), within the same 256B row
        int c = lane >> 2;
        int sw = c ^ (node & 7);
        aggx[(size_t)node * 64 + sw * 4 + (lane & 3)] = o;
    }
}

// ---------------- layer MFMA (no LDS): hout = relu(LN(X@W + b)*g + lnb) + hin ----------------
// X fragments loaded DIRECTLY from pre-swizzled global aggx
__global__ __launch_bounds__(256) void k_layer(const unsigned* __restrict__ hin,   // residual, [n*64] bf16 pairs
                                               unsigned* __restrict__ hout,
                                               const unsigned* __restrict__ aggx,  // pre-swizzled X (padded)
                                               const unsigned short* __restrict__ Wt,  // [128][128] bf16
                                               const float* __restrict__ bias, const float* __restrict__ g,
                                               const float* __restrict__ lnb, int n) {
    const int tid = threadIdx.x;
    const int row0 = blockIdx.x * RT;
    const int lane = tid & 63;
    const int w = tid >> 6;
    const int l15 = lane & 15, lg = lane >> 4;
    const int xrow = w * 16 + l15;
    const int grow = row0 + xrow;   // may be >= n for tail block; aggx is padded

    const unsigned short* xg = reinterpret_cast<const unsigned short*>(aggx) + (size_t)grow * HID;

    f32x4 acc[8];
#pragma unroll
    for (int t = 0; t < 8; ++t) acc[t] = (f32x4){0.f, 0.f, 0.f, 0.f};

#pragma unroll
    for (int kc = 0; kc < 4; ++kc) {
        int bc = (kc * 4 + lg) ^ (xrow & 7);
        bf16x8 bfrag = *reinterpret_cast<const bf16x8*>(xg + bc * 8);
        const unsigned short* wp = Wt + (size_t)l15 * HID + kc * 32 + lg * 8;
        bf16x8 af[8];
#pragma unroll
        for (int t = 0; t < 8; ++t) af[t] = *reinterpret_cast<const bf16x8*>(wp + (size_t)t * 16 * HID);
#pragma unroll
        for (int t = 0; t < 8; ++t)
            acc[t] = __builtin_amdgcn_mfma_f32_16x16x32_bf16(af[t], bfrag, acc[t], 0, 0, 0);
    }

    float s = 0.f, q = 0.f;
#pragma unroll
    for (int t = 0; t < 8; ++t) {
        int c0 = t * 16 + lg * 4;
        f32x4 bb = *reinterpret_cast<const f32x4*>(bias + c0);
        acc[t] = acc[t] + bb;
        s += acc[t].x + acc[t].y + acc[t].z + acc[t].w;
        q += acc[t].x * acc[t].x + acc[t].y * acc[t].y + acc[t].z * acc[t].z + acc[t].w * acc[t].w;
    }
    s += __shfl_xor(s, 16, 64);
    s += __shfl_xor(s, 32, 64);
    q += __shfl_xor(q, 16, 64);
    q += __shfl_xor(q, 32, 64);
    float mu = s * (1.0f / HID);
    float var = q * (1.0f / HID) - mu * mu;
    float rs = rsqrtf(var + LN_EPS);

    if (grow < n) {
#pragma unroll
        for (int t = 0; t < 8; ++t) {
            int c0 = t * 16 + lg * 4;
            uint2 rv = *reinterpret_cast<const uint2*>(hin + (size_t)grow * 64 + t * 8 + lg * 2);
            f32x4 gv = *reinterpret_cast<const f32x4*>(g + c0);
            f32x4 lb = *reinterpret_cast<const f32x4*>(lnb + c0);
            float o0 = fmaxf((acc[t].x - mu) * rs * gv.x + lb.x, 0.f) + bflo(rv.x);
            float o1 = fmaxf((acc[t].y - mu) * rs * gv.y + lb.y, 0.f) + bfhi(rv.x);
            float o2 = fmaxf((acc[t].z - mu) * rs * gv.z + lb.z, 0.f) + bflo(rv.y);
            float o3 = fmaxf((acc[t].w - mu) * rs * gv.w + lb.w, 0.f) + bfhi(rv.y);
            uint2 p;
            p.x = f2bf(o0) | (f2bf(o1) << 16);
            p.y = f2bf(o2) | (f2bf(o3) << 16);
            *reinterpret_cast<uint2*>(hout + (size_t)grow * 64 + t * 8 + lg * 2) = p;
        }
    }
}

// ---------------- final: accum[c] = sum over rows < n_act of h[r][c] ----------------
__global__ __launch_bounds__(256) void k_rowsum(const unsigned* __restrict__ hb, const int* __restrict__ n_act_p,
                                                float* __restrict__ accum, int n) {
    __shared__ float sred[256 * 2];
    int na = *n_act_p;
    int row0 = blockIdx.x * 256;
    int c = threadIdx.x & 63;    // col pair
    int sub = threadIdx.x >> 6;  // 0..3
    int rend = row0 + 256;
    if (rend > na) rend = na;
    float sx = 0.f, sy = 0.f;
    for (int r = row0 + sub; r < rend; r += 4) {
        unsigned v = hb[(size_t)r * 64 + c];
        sx += bflo(v);
        sy += bfhi(v);
    }
    sred[threadIdx.x * 2] = sx;
    sred[threadIdx.x * 2 + 1] = sy;
    __syncthreads();
    if (threadIdx.x < 64) {
        float tx = sred[threadIdx.x * 2] + sred[(threadIdx.x + 64) * 2] +
                   sred[(threadIdx.x + 128) * 2] + sred[(threadIdx.x + 192) * 2];
        float ty = sred[threadIdx.x * 2 + 1] + sred[(threadIdx.x + 64) * 2 + 1] +
                   sred[(threadIdx.x + 128) * 2 + 1] + sred[(threadIdx.x + 192) * 2 + 1];
        if (row0 < na) {
            atomicAdd(&accum[2 * threadIdx.x], tx);
            atomicAdd(&accum[2 * threadIdx.x + 1], ty);
        }
    }
}

__global__ void k_out(const float* __restrict__ accum, const int* __restrict__ n_act_p,
                      const float* __restrict__ W_out, const float* __restrict__ b_out,
                      float* __restrict__ out) {
    __shared__ float m[HID];
    int c = threadIdx.x;
    float na = (float)(*n_act_p);
    m[c] = accum[c] / na;
    __syncthreads();
    float s = b_out[c];
    for (int k = 0; k < HID; ++k) s += m[k] * W_out[k * HID + c];
    out[c] = s;
}

extern "C" void kernel_launch(void* const* d_in, const int* in_sizes, int n_in,
                              void* d_out, int out_size, void* d_ws, size_t ws_size,
                              hipStream_t stream) {
    const int n  = in_sizes[0] / INP;   // 50000
    const int nE = in_sizes[1] / 2;     // 800000
    const float* x    = (const float*)d_in[0];
    const int*   ei   = (const int*)d_in[1];
    const int*   src  = ei;
    const int*   dst  = ei + nE;
    const int*   nact = (const int*)d_in[2];
    const float* W_in = (const float*)d_in[3];
    const float* b_in = (const float*)d_in[4];
    const float* W_l  = (const float*)d_in[5];
    const float* b_l  = (const float*)d_in[6];
    const float* lng  = (const float*)d_in[7];
    const float* lnb  = (const float*)d_in[8];
    const float* W_o  = (const float*)d_in[9];
    const float* b_o  = (const float*)d_in[10];

    char* ws = (char*)d_ws;
    size_t off = 0;
    auto alloc = [&](size_t bytes) {
        void* p = ws + off;
        off = (off + bytes + 255) & ~((size_t)255);
        return p;
    };
    unsigned* hbA  = (unsigned*)alloc((size_t)n * 64 * 4);
    unsigned* hbB  = (unsigned*)alloc((size_t)n * 64 * 4);
    unsigned* aggx = (unsigned*)alloc((size_t)(n + RT) * 64 * 4);  // +RT rows pad for tail-block frag reads
    int*   cnt  = (int*)alloc((size_t)n * 4);
    int*   rowp = (int*)alloc((size_t)(n + 1) * 4);
    int*   curs = (int*)alloc((size_t)n * 4);
    float* invd = (float*)alloc((size_t)n * 4);
    int*   csrc = (int*)alloc((size_t)nE * 4);
    int*   bsum = (int*)alloc(1024);
    float* accum = (float*)alloc(HID * 4);
    unsigned short* Wt_in = (unsigned short*)alloc(128 * 64 * 2);
    unsigned short* Wt_l  = (unsigned short*)alloc(3 * 128 * 128 * 2);

    hipMemsetAsync(cnt, 0, (size_t)n * 4, stream);
    hipMemsetAsync(accum, 0, HID * 4, stream);

    int nb = (n + 255) / 256;
    int e8grid = (nE / 8 + 255) / 256 + 1;   // 8 edges/thread (extra block covers tail)
    w_prep<<<(128 * 64 + 3 * 128 * 128 + 255) / 256, 256, 0, stream>>>(W_in, W_l, Wt_in, Wt_l);
    k_count<<<e8grid, 256, 0, stream>>>(dst, nE, cnt);
    k_scan1<<<nb, 256, 0, stream>>>(cnt, n, rowp, bsum);
    k_scan2<<<1, 256, 0, stream>>>(bsum, nb);
    k_scan3<<<nb, 256, 0, stream>>>(rowp, bsum, cnt, n, nE, curs, invd);
    k_fill<<<e8grid, 256, 0, stream>>>(src, dst, nE, curs, csrc);

    int tgrid = (n + RT - 1) / RT;
    k_inproj<<<tgrid, 256, 0, stream>>>(x, Wt_in, b_in, hbA, n);

    const int aggBlocks = 2048;
    const int nwaves = aggBlocks * 4;
    const unsigned* hin = hbA;
    unsigned* hout = hbB;
    for (int l = 0; l < 3; ++l) {
        k_agg<<<aggBlocks, 256, 0, stream>>>(hin, rowp, csrc, invd, aggx, n, nwaves);
        k_layer<<<tgrid, 256, 0, stream>>>(hin, hout, aggx,
                                           Wt_l + (size_t)l * 128 * 128,
                                           b_l + l * HID, lng + l * HID, lnb + l * HID, n);
        const unsigned* t = hout;
        hout = (unsigned*)hin;
        hin = t;
    }
    k_rowsum<<<(n + 255) / 256, 256, 0, stream>>>(hin, nact, accum, n);
    k_out<<<1, HID, 0, stream>>>(accum, nact, W_o, b_o, (float*)d_out);
}

// Round 8
// 307.766 us; speedup vs baseline: 1.4818x; 1.0513x over previous
//
#include <hip/hip_runtime.h>

#define HID 128
#define INP 64
#define LN_EPS 1e-5f
#define RT 64   // rows per block in GEMM kernels

typedef __attribute__((ext_vector_type(8))) short bf16x8;
typedef __attribute__((ext_vector_type(4))) float f32x4;

__device__ __forceinline__ unsigned f2bf(float f) {
    unsigned u = __float_as_uint(f);
    return (u + 0x7FFFu + ((u >> 16) & 1u)) >> 16;   // RNE
}
__device__ __forceinline__ float bflo(unsigned v) { return __uint_as_float(v << 16); }
__device__ __forceinline__ float bfhi(unsigned v) { return __uint_as_float(v & 0xFFFF0000u); }

// ---------------- CSR count (16 edges/thread) + fused weight prep ----------------
__global__ __launch_bounds__(256) void k_count(const int* __restrict__ dst, int nE, int* __restrict__ cnt,
                                               int nEdgeThreads,
                                               const float* __restrict__ W_in, const float* __restrict__ W_l,
                                               unsigned short* __restrict__ Wt_in, unsigned short* __restrict__ Wt_l) {
    int t = blockIdx.x * 256 + threadIdx.x;
    if (t < nEdgeThreads) {
        int base = t * 16;
        if (base + 16 <= nE) {
#pragma unroll
            for (int j = 0; j < 4; ++j) {
                int4 d = *reinterpret_cast<const int4*>(dst + base + j * 4);
                atomicAdd(&cnt[d.x], 1);
                atomicAdd(&cnt[d.y], 1);
                atomicAdd(&cnt[d.z], 1);
                atomicAdd(&cnt[d.w], 1);
            }
        } else {
            for (int e = base; e < nE; ++e) atomicAdd(&cnt[dst[e]], 1);
        }
        return;
    }
    int i = t - nEdgeThreads;
    if (i < 128 * 64) {
        int col = i >> 6, k = i & 63;
        Wt_in[i] = (unsigned short)f2bf(W_in[(size_t)k * HID + col]);
    } else if (i < 128 * 64 + 3 * 128 * 128) {
        int j = i - 128 * 64;
        int l = j >> 14, r = j & 16383;
        int col = r >> 7, k = r & 127;
        Wt_l[j] = (unsigned short)f2bf(W_l[(size_t)l * 16384 + (size_t)k * HID + col]);
    }
}

__global__ void k_scan1(const int* __restrict__ cnt, int n, int* __restrict__ rowp, int* __restrict__ bsum) {
    __shared__ int s[256];
    int i = blockIdx.x * 256 + threadIdx.x;
    int v = (i < n) ? cnt[i] : 0;
    s[threadIdx.x] = v;
    __syncthreads();
    for (int off = 1; off < 256; off <<= 1) {
        int t = (threadIdx.x >= off) ? s[threadIdx.x - off] : 0;
        __syncthreads();
        s[threadIdx.x] += t;
        __syncthreads();
    }
    if (i < n) rowp[i] = s[threadIdx.x] - v;  // exclusive
    if (threadIdx.x == 255) bsum[blockIdx.x] = s[255];
}

__global__ void k_scan2(int* __restrict__ bsum, int nb) {
    __shared__ int s[256];
    int v = (threadIdx.x < nb) ? bsum[threadIdx.x] : 0;
    s[threadIdx.x] = v;
    __syncthreads();
    for (int off = 1; off < 256; off <<= 1) {
        int t = (threadIdx.x >= off) ? s[threadIdx.x - off] : 0;
        __syncthreads();
        s[threadIdx.x] += t;
        __syncthreads();
    }
    if (threadIdx.x < nb) bsum[threadIdx.x] = s[threadIdx.x] - v;
}

__global__ void k_scan3(int* __restrict__ rowp, const int* __restrict__ bsum, const int* __restrict__ cnt,
                        int n, int nE, int* __restrict__ cursor, float* __restrict__ invd) {
    int i = blockIdx.x * 256 + threadIdx.x;
    if (i < n) {
        int rp = rowp[i] + bsum[blockIdx.x];
        rowp[i] = rp;
        cursor[i] = rp;
        int c = cnt[i];
        invd[i] = 1.0f / (float)(c > 1 ? c : 1);
    } else if (i == n) {
        rowp[n] = nE;
    }
}

// 16 edges/thread: pipelined atomic-returns + fire-and-forget scatter stores
__global__ __launch_bounds__(256) void k_fill(const int* __restrict__ src, const int* __restrict__ dst, int nE,
                                              int* __restrict__ cursor, int* __restrict__ csrc) {
    int t = blockIdx.x * 256 + threadIdx.x;
    int base = t * 16;
    if (base + 16 <= nE) {
        int4 d[4], s[4];
#pragma unroll
        for (int j = 0; j < 4; ++j) {
            d[j] = *reinterpret_cast<const int4*>(dst + base + j * 4);
            s[j] = *reinterpret_cast<const int4*>(src + base + j * 4);
        }
        int p[16];
#pragma unroll
        for (int j = 0; j < 4; ++j) {
            p[j * 4 + 0] = atomicAdd(&cursor[d[j].x], 1);
            p[j * 4 + 1] = atomicAdd(&cursor[d[j].y], 1);
            p[j * 4 + 2] = atomicAdd(&cursor[d[j].z], 1);
            p[j * 4 + 3] = atomicAdd(&cursor[d[j].w], 1);
        }
#pragma unroll
        for (int j = 0; j < 4; ++j) {
            csrc[p[j * 4 + 0]] = s[j].x;
            csrc[p[j * 4 + 1]] = s[j].y;
            csrc[p[j * 4 + 2]] = s[j].z;
            csrc[p[j * 4 + 3]] = s[j].w;
        }
    } else if (base < nE) {
        for (int e = base; e < nE; ++e) {
            int pp = atomicAdd(&cursor[dst[e]], 1);
            csrc[pp] = src[e];
        }
    }
}

// ---------------- in-projection (MFMA): hb = bf16(x @ W_in + b_in) ----------------
__global__ __launch_bounds__(256) void k_inproj(const float* __restrict__ x,
                                                const unsigned short* __restrict__ Wt,  // [128][64] bf16
                                                const float* __restrict__ b,
                                                unsigned* __restrict__ hout, int n) {
    __shared__ unsigned short xs[RT * INP];  // 8 KB, swizzled
    const int tid = threadIdx.x;
    const int row0 = blockIdx.x * RT;

#pragma unroll
    for (int j = 0; j < 2; ++j) {
        int fid = tid + j * 256;
        int r = fid >> 3, c = fid & 7;
        int grow = row0 + r;
        unsigned o[4] = {0, 0, 0, 0};
        if (grow < n) {
            float4 v0 = *reinterpret_cast<const float4*>(x + (size_t)grow * INP + c * 8);
            float4 v1 = *reinterpret_cast<const float4*>(x + (size_t)grow * INP + c * 8 + 4);
            o[0] = f2bf(v0.x) | (f2bf(v0.y) << 16);
            o[1] = f2bf(v0.z) | (f2bf(v0.w) << 16);
            o[2] = f2bf(v1.x) | (f2bf(v1.y) << 16);
            o[3] = f2bf(v1.z) | (f2bf(v1.w) << 16);
        }
        int sw = c ^ (r & 7);
        *reinterpret_cast<uint4*>(xs + r * INP + sw * 8) = make_uint4(o[0], o[1], o[2], o[3]);
    }
    __syncthreads();

    const int l = tid & 63;
    const int w = tid >> 6;
    const int l15 = l & 15, lg = l >> 4;
    const int xrow = w * 16 + l15;

    f32x4 acc[8];
#pragma unroll
    for (int t = 0; t < 8; ++t) acc[t] = (f32x4){0.f, 0.f, 0.f, 0.f};

#pragma unroll
    for (int kc = 0; kc < 2; ++kc) {
        int bc = (kc * 4 + lg) ^ (xrow & 7);
        bf16x8 bfrag = *reinterpret_cast<const bf16x8*>(xs + xrow * INP + bc * 8);
        const unsigned short* wp = Wt + (size_t)l15 * INP + kc * 32 + lg * 8;
        bf16x8 af[8];
#pragma unroll
        for (int t = 0; t < 8; ++t) af[t] = *reinterpret_cast<const bf16x8*>(wp + (size_t)t * 16 * INP);
#pragma unroll
        for (int t = 0; t < 8; ++t)
            acc[t] = __builtin_amdgcn_mfma_f32_16x16x32_bf16(af[t], bfrag, acc[t], 0, 0, 0);
    }

    int grow = row0 + xrow;
    if (grow < n) {
#pragma unroll
        for (int t = 0; t < 8; ++t) {
            int c0 = t * 16 + lg * 4;
            f32x4 bb = *reinterpret_cast<const f32x4*>(b + c0);
            f32x4 o = acc[t] + bb;
            uint2 p;
            p.x = f2bf(o.x) | (f2bf(o.y) << 16);
            p.y = f2bf(o.z) | (f2bf(o.w) << 16);
            *reinterpret_cast<uint2*>(hout + (size_t)grow * 64 + t * 8 + lg * 2) = p;
        }
    }
}

// ---------------- aggregation: aggx[v] = bf16( hb[v] + (sum_{u in N(v)} hb[u]) * invd[v] ), PRE-SWIZZLED ----------------
// one wave per node; lane-parallel index prefetch + __shfl broadcast -> all gathers in flight
__global__ __launch_bounds__(256) void k_agg(const unsigned* __restrict__ hb, const int* __restrict__ rowp,
                                             const int* __restrict__ csrc, const float* __restrict__ invd,
                                             unsigned* __restrict__ aggx, int n) {
    int node = blockIdx.x * 4 + (threadIdx.x >> 6);
    if (node >= n) return;
    int lane = threadIdx.x & 63;
    int e0 = rowp[node], e1 = rowp[node + 1];
    int deg = e1 - e0;
    unsigned self = hb[(size_t)node * 64 + lane];
    float inv = invd[node];
    float ax = 0.f, ay = 0.f;

    for (int base = 0; base < deg; base += 64) {
        int m = deg - base;
        if (m > 64) m = 64;
        int myidx = (base + lane < deg) ? csrc[e0 + base + lane] : 0;
        int j = 0;
        for (; j + 8 <= m; j += 8) {
            int s0 = __shfl(myidx, j + 0);
            int s1 = __shfl(myidx, j + 1);
            int s2 = __shfl(myidx, j + 2);
            int s3 = __shfl(myidx, j + 3);
            int s4 = __shfl(myidx, j + 4);
            int s5 = __shfl(myidx, j + 5);
            int s6 = __shfl(myidx, j + 6);
            int s7 = __shfl(myidx, j + 7);
            unsigned v0 = hb[(size_t)s0 * 64 + lane];
            unsigned v1 = hb[(size_t)s1 * 64 + lane];
            unsigned v2 = hb[(size_t)s2 * 64 + lane];
            unsigned v3 = hb[(size_t)s3 * 64 + lane];
            unsigned v4 = hb[(size_t)s4 * 64 + lane];
            unsigned v5 = hb[(size_t)s5 * 64 + lane];
            unsigned v6 = hb[(size_t)s6 * 64 + lane];
            unsigned v7 = hb[(size_t)s7 * 64 + lane];
            ax += ((bflo(v0) + bflo(v1)) + (bflo(v2) + bflo(v3))) +
                  ((bflo(v4) + bflo(v5)) + (bflo(v6) + bflo(v7)));
            ay += ((bfhi(v0) + bfhi(v1)) + (bfhi(v2) + bfhi(v3))) +
                  ((bfhi(v4) + bfhi(v5)) + (bfhi(v6) + bfhi(v7)));
        }
        for (; j < m; ++j) {
            int s0 = __shfl(myidx, j);
            unsigned v = hb[(size_t)s0 * 64 + lane];
            ax += bflo(v);
            ay += bfhi(v);
        }
    }

    float xlo = bflo(self) + ax * inv;
    float xhi = bfhi(self) + ay * inv;
    unsigned o = f2bf(xlo) | (f2bf(xhi) << 16);
    // swizzled position: 16B chunk c -> c ^ (row&7), within the same 256B row
    int c = lane >> 2;
    int sw = c ^ (node & 7);
    aggx[(size_t)node * 64 + sw * 4 + (lane & 3)] = o;
}

// ---------------- layer MFMA (no LDS): hout = relu(LN(X@W + b)*g + lnb) + hin ----------------
__global__ __launch_bounds__(256) void k_layer(const unsigned* __restrict__ hin,   // residual, [n*64] bf16 pairs
                                               unsigned* __restrict__ hout,
                                               const unsigned* __restrict__ aggx,  // pre-swizzled X (padded)
                                               const unsigned short* __restrict__ Wt,  // [128][128] bf16
                                               const float* __restrict__ bias, const float* __restrict__ g,
                                               const float* __restrict__ lnb, int n) {
    const int tid = threadIdx.x;
    const int row0 = blockIdx.x * RT;
    const int lane = tid & 63;
    const int w = tid >> 6;
    const int l15 = lane & 15, lg = lane >> 4;
    const int xrow = w * 16 + l15;
    const int grow = row0 + xrow;   // may be >= n for tail block; aggx is padded

    const unsigned short* xg = reinterpret_cast<const unsigned short*>(aggx) + (size_t)grow * HID;

    f32x4 acc[8];
#pragma unroll
    for (int t = 0; t < 8; ++t) acc[t] = (f32x4){0.f, 0.f, 0.f, 0.f};

#pragma unroll
    for (int kc = 0; kc < 4; ++kc) {
        int bc = (kc * 4 + lg) ^ (xrow & 7);
        bf16x8 bfrag = *reinterpret_cast<const bf16x8*>(xg + bc * 8);
        const unsigned short* wp = Wt + (size_t)l15 * HID + kc * 32 + lg * 8;
        bf16x8 af[8];
#pragma unroll
        for (int t = 0; t < 8; ++t) af[t] = *reinterpret_cast<const bf16x8*>(wp + (size_t)t * 16 * HID);
#pragma unroll
        for (int t = 0; t < 8; ++t)
            acc[t] = __builtin_amdgcn_mfma_f32_16x16x32_bf16(af[t], bfrag, acc[t], 0, 0, 0);
    }

    float s = 0.f, q = 0.f;
#pragma unroll
    for (int t = 0; t < 8; ++t) {
        int c0 = t * 16 + lg * 4;
        f32x4 bb = *reinterpret_cast<const f32x4*>(bias + c0);
        acc[t] = acc[t] + bb;
        s += acc[t].x + acc[t].y + acc[t].z + acc[t].w;
        q += acc[t].x * acc[t].x + acc[t].y * acc[t].y + acc[t].z * acc[t].z + acc[t].w * acc[t].w;
    }
    s += __shfl_xor(s, 16, 64);
    s += __shfl_xor(s, 32, 64);
    q += __shfl_xor(q, 16, 64);
    q += __shfl_xor(q, 32, 64);
    float mu = s * (1.0f / HID);
    float var = q * (1.0f / HID) - mu * mu;
    float rs = rsqrtf(var + LN_EPS);

    if (grow < n) {
#pragma unroll
        for (int t = 0; t < 8; ++t) {
            int c0 = t * 16 + lg * 4;
            uint2 rv = *reinterpret_cast<const uint2*>(hin + (size_t)grow * 64 + t * 8 + lg * 2);
            f32x4 gv = *reinterpret_cast<const f32x4*>(g + c0);
            f32x4 lb = *reinterpret_cast<const f32x4*>(lnb + c0);
            float o0 = fmaxf((acc[t].x - mu) * rs * gv.x + lb.x, 0.f) + bflo(rv.x);
            float o1 = fmaxf((acc[t].y - mu) * rs * gv.y + lb.y, 0.f) + bfhi(rv.x);
            float o2 = fmaxf((acc[t].z - mu) * rs * gv.z + lb.z, 0.f) + bflo(rv.y);
            float o3 = fmaxf((acc[t].w - mu) * rs * gv.w + lb.w, 0.f) + bfhi(rv.y);
            uint2 p;
            p.x = f2bf(o0) | (f2bf(o1) << 16);
            p.y = f2bf(o2) | (f2bf(o3) << 16);
            *reinterpret_cast<uint2*>(hout + (size_t)grow * 64 + t * 8 + lg * 2) = p;
        }
    }
}

// ---------------- final: accum[c] = sum over rows < n_act of h[r][c] ----------------
__global__ __launch_bounds__(256) void k_rowsum(const unsigned* __restrict__ hb, const int* __restrict__ n_act_p,
                                                float* __restrict__ accum, int n) {
    __shared__ float sred[256 * 2];
    int na = *n_act_p;
    int row0 = blockIdx.x * 256;
    int c = threadIdx.x & 63;    // col pair
    int sub = threadIdx.x >> 6;  // 0..3
    int rend = row0 + 256;
    if (rend > na) rend = na;
    float sx = 0.f, sy = 0.f;
    for (int r = row0 + sub; r < rend; r += 4) {
        unsigned v = hb[(size_t)r * 64 + c];
        sx += bflo(v);
        sy += bfhi(v);
    }
    sred[threadIdx.x * 2] = sx;
    sred[threadIdx.x * 2 + 1] = sy;
    __syncthreads();
    if (threadIdx.x < 64) {
        float tx = sred[threadIdx.x * 2] + sred[(threadIdx.x + 64) * 2] +
                   sred[(threadIdx.x + 128) * 2] + sred[(threadIdx.x + 192) * 2];
        float ty = sred[threadIdx.x * 2 + 1] + sred[(threadIdx.x + 64) * 2 + 1] +
                   sred[(threadIdx.x + 128) * 2 + 1] + sred[(threadIdx.x + 192) * 2 + 1];
        if (row0 < na) {
            atomicAdd(&accum[2 * threadIdx.x], tx);
            atomicAdd(&accum[2 * threadIdx.x + 1], ty);
        }
    }
}

__global__ void k_out(const float* __restrict__ accum, const int* __restrict__ n_act_p,
                      const float* __restrict__ W_out, const float* __restrict__ b_out,
                      float* __restrict__ out) {
    __shared__ float m[HID];
    int c = threadIdx.x;
    float na = (float)(*n_act_p);
    m[c] = accum[c] / na;
    __syncthreads();
    float s = b_out[c];
    for (int k = 0; k < HID; ++k) s += m[k] * W_out[k * HID + c];
    out[c] = s;
}

extern "C" void kernel_launch(void* const* d_in, const int* in_sizes, int n_in,
                              void* d_out, int out_size, void* d_ws, size_t ws_size,
                              hipStream_t stream) {
    const int n  = in_sizes[0] / INP;   // 50000
    const int nE = in_sizes[1] / 2;     // 800000
    const float* x    = (const float*)d_in[0];
    const int*   ei   = (const int*)d_in[1];
    const int*   src  = ei;
    const int*   dst  = ei + nE;
    const int*   nact = (const int*)d_in[2];
    const float* W_in = (const float*)d_in[3];
    const float* b_in = (const float*)d_in[4];
    const float* W_l  = (const float*)d_in[5];
    const float* b_l  = (const float*)d_in[6];
    const float* lng  = (const float*)d_in[7];
    const float* lnb  = (const float*)d_in[8];
    const float* W_o  = (const float*)d_in[9];
    const float* b_o  = (const float*)d_in[10];

    char* ws = (char*)d_ws;
    size_t off = 0;
    auto alloc = [&](size_t bytes) {
        void* p = ws + off;
        off = (off + bytes + 255) & ~((size_t)255);
        return p;
    };
    unsigned* hbA  = (unsigned*)alloc((size_t)n * 64 * 4);
    unsigned* hbB  = (unsigned*)alloc((size_t)n * 64 * 4);
    unsigned* aggx = (unsigned*)alloc((size_t)(n + RT) * 64 * 4);  // +RT rows pad for tail-block frag reads
    int*   cnt  = (int*)alloc((size_t)n * 4);
    int*   rowp = (int*)alloc((size_t)(n + 1) * 4);
    int*   curs = (int*)alloc((size_t)n * 4);
    float* invd = (float*)alloc((size_t)n * 4);
    int*   csrc = (int*)alloc((size_t)nE * 4);
    int*   bsum = (int*)alloc(1024);
    float* accum = (float*)alloc(HID * 4);
    unsigned short* Wt_in = (unsigned short*)alloc(128 * 64 * 2);
    unsigned short* Wt_l  = (unsigned short*)alloc(3 * 128 * 128 * 2);

    hipMemsetAsync(cnt, 0, (size_t)n * 4, stream);
    hipMemsetAsync(accum, 0, HID * 4, stream);

    int nb = (n + 255) / 256;
    int nEdgeThreads = (nE + 15) / 16;                       // 16 edges/thread
    int nPrep = 128 * 64 + 3 * 128 * 128;
    int cpgrid = (nEdgeThreads + nPrep + 255) / 256;
    k_count<<<cpgrid, 256, 0, stream>>>(dst, nE, cnt, nEdgeThreads, W_in, W_l, Wt_in, Wt_l);
    k_scan1<<<nb, 256, 0, stream>>>(cnt, n, rowp, bsum);
    k_scan2<<<1, 256, 0, stream>>>(bsum, nb);
    k_scan3<<<nb, 256, 0, stream>>>(rowp, bsum, cnt, n, nE, curs, invd);
    k_fill<<<(nEdgeThreads + 255) / 256, 256, 0, stream>>>(src, dst, nE, curs, csrc);

    int tgrid = (n + RT - 1) / RT;
    k_inproj<<<tgrid, 256, 0, stream>>>(x, Wt_in, b_in, hbA, n);

    const unsigned* hin = hbA;
    unsigned* hout = hbB;
    for (int l = 0; l < 3; ++l) {
        k_agg<<<(n + 3) / 4, 256, 0, stream>>>(hin, rowp, csrc, invd, aggx, n);
        k_layer<<<tgrid, 256, 0, stream>>>(hin, hout, aggx,
                                           Wt_l + (size_t)l * 128 * 128,
                                           b_l + l * HID, lng + l * HID, lnb + l * HID, n);
        const unsigned* t = hout;
        hout = (unsigned*)hin;
        hin = t;
    }
    k_rowsum<<<(n + 255) / 256, 256, 0, stream>>>(hin, nact, accum, n);
    k_out<<<1, HID, 0, stream>>>(accum, nact, W_o, b_o, (float*)d_out);
}